// Round 5
// baseline (275.077 us; speedup 1.0000x reference)
//
#include <hip/hip_runtime.h>

#define B_   32
#define S_   8192
#define T_   256
#define IN_  4096
#define H_   512
#define OUT_ 10
#define CAP_ 192   // max events per (b,t) bucket; max observed ~70 (Poisson(32))
#define FB_  16    // steps per register buffer in simfast_k

// ---------------------------------------------------------------------------
// Fused prep: z=0 transpose w_in, z=1 transpose w_rec, z=2 event scatter.
// block = (32,8)
// ---------------------------------------------------------------------------
__global__ void prep_k(const float* __restrict__ w_in, const float* __restrict__ w_rec,
                       const int4* __restrict__ x,
                       float* __restrict__ w_in_T, float* __restrict__ w_rec_T,
                       int* __restrict__ cnt, unsigned* __restrict__ data) {
    int zz = blockIdx.z;
    int tx = threadIdx.x, ty = threadIdx.y;
    if (zz == 2) {
        // ---- scatter: key = (pos<<14)|(s<<1)|val; max key per pos = last event
        int flat = blockIdx.y * gridDim.x + blockIdx.x;
        if (flat >= (B_ * S_) / 256) return;
        int e = flat * 256 + ty * 32 + tx;
        int4 ev = x[e];                       // cx, cy, val, ts
        int b = e >> 13;                      // S_ = 8192
        int s = e & (S_ - 1);
        unsigned pos = (unsigned)(ev.x * ev.y);
        unsigned key = (pos << 14) | ((unsigned)s << 1) | (unsigned)ev.z;
        int bucket = b * T_ + ev.w;
        int slot = atomicAdd(&cnt[bucket], 1);
        if (slot < CAP_) data[bucket * CAP_ + slot] = key;
        return;
    }
    // ---- transpose src[R][C] -> dst[C][R]
    const float* src = zz ? w_rec : w_in;
    float* dst = zz ? w_rec_T : w_in_T;
    const int R = H_, C = zz ? H_ : IN_;
    int bx = blockIdx.x * 32, by = blockIdx.y * 32;
    if (bx >= C || by >= R) return;
    __shared__ float tile[32][33];
    #pragma unroll
    for (int k = 0; k < 32; k += 8) {
        int r = by + ty + k, c = bx + tx;
        if (r < R && c < C) tile[ty + k][tx] = src[(size_t)r * C + c];
    }
    __syncthreads();
    #pragma unroll
    for (int k = 0; k < 32; k += 8) {
        int c = bx + ty + k, r = by + tx;
        if (c < C && r < R) dst[(size_t)c * R + r] = tile[tx][ty + k];
    }
}

// ---------------------------------------------------------------------------
// Per-bucket dedup + input-current accumulation (block per (b,t), 512 thr).
// No early-break scans (8-deep batched LDS reads), ballot-based compaction.
// ---------------------------------------------------------------------------
__global__ __launch_bounds__(512) void incur_k(const int* __restrict__ cnt,
                                               const unsigned* __restrict__ data,
                                               const float* __restrict__ w_in_T,
                                               float* __restrict__ in_cur) {
    int bucket = blockIdx.x;       // b*T_ + t
    int b = bucket >> 8;
    int t = bucket & (T_ - 1);
    __shared__ unsigned keys[CAP_];
    __shared__ unsigned long long wball[8];
    __shared__ unsigned short plist[CAP_];
    int tid = threadIdx.x;
    int n = cnt[bucket]; if (n > CAP_) n = CAP_;
    if (tid < n) keys[tid] = data[bucket * CAP_ + tid];
    __syncthreads();
    bool win = false;
    unsigned ki = 0;
    if (tid < n) {
        ki = keys[tid];
        unsigned pi = ki >> 14;
        bool dead = false;
        for (int j = 0; j < n; j += 8) {   // batched, no break: loads pipeline
            unsigned a0 = keys[j];
            unsigned a1 = keys[j + 1 < n ? j + 1 : 0];
            unsigned a2 = keys[j + 2 < n ? j + 2 : 0];
            unsigned a3 = keys[j + 3 < n ? j + 3 : 0];
            unsigned a4 = keys[j + 4 < n ? j + 4 : 0];
            unsigned a5 = keys[j + 5 < n ? j + 5 : 0];
            unsigned a6 = keys[j + 6 < n ? j + 6 : 0];
            unsigned a7 = keys[j + 7 < n ? j + 7 : 0];
            dead |= (((a0 >> 14) == pi) & (a0 > ki));
            dead |= ((j + 1 < n) & ((a1 >> 14) == pi) & (a1 > ki));
            dead |= ((j + 2 < n) & ((a2 >> 14) == pi) & (a2 > ki));
            dead |= ((j + 3 < n) & ((a3 >> 14) == pi) & (a3 > ki));
            dead |= ((j + 4 < n) & ((a4 >> 14) == pi) & (a4 > ki));
            dead |= ((j + 5 < n) & ((a5 >> 14) == pi) & (a5 > ki));
            dead |= ((j + 6 < n) & ((a6 >> 14) == pi) & (a6 > ki));
            dead |= ((j + 7 < n) & ((a7 >> 14) == pi) & (a7 > ki));
        }
        win = ((ki & 1u) != 0u) && !dead;  // val==1 and survived
    }
    unsigned long long ball = __ballot(win);
    if ((tid & 63) == 0) wball[tid >> 6] = ball;
    int m = __syncthreads_count(win);      // barrier: wball visible, m = #winners
    if (win) {
        int wid = tid >> 6;
        int r = __popcll(ball & ((1ull << (tid & 63)) - 1ull));
        for (int j = 0; j < wid; ++j) r += __popcll(wball[j]);
        plist[r] = (unsigned short)(ki >> 14);
    }
    __syncthreads();                       // plist ready
    float acc = 0.f;
    for (int k = 0; k < m; k += 8) {       // 8 row-loads in flight per round
        int i0 = k + 0 < m ? k + 0 : m - 1;  float g0 = w_in_T[(int)plist[i0] * H_ + tid];
        int i1 = k + 1 < m ? k + 1 : m - 1;  float g1 = w_in_T[(int)plist[i1] * H_ + tid];
        int i2 = k + 2 < m ? k + 2 : m - 1;  float g2 = w_in_T[(int)plist[i2] * H_ + tid];
        int i3 = k + 3 < m ? k + 3 : m - 1;  float g3 = w_in_T[(int)plist[i3] * H_ + tid];
        int i4 = k + 4 < m ? k + 4 : m - 1;  float g4 = w_in_T[(int)plist[i4] * H_ + tid];
        int i5 = k + 5 < m ? k + 5 : m - 1;  float g5 = w_in_T[(int)plist[i5] * H_ + tid];
        int i6 = k + 6 < m ? k + 6 : m - 1;  float g6 = w_in_T[(int)plist[i6] * H_ + tid];
        int i7 = k + 7 < m ? k + 7 : m - 1;  float g7 = w_in_T[(int)plist[i7] * H_ + tid];
        acc = acc + (k + 0 < m ? g0 : 0.f);
        acc = acc + (k + 1 < m ? g1 : 0.f);
        acc = acc + (k + 2 < m ? g2 : 0.f);
        acc = acc + (k + 3 < m ? g3 : 0.f);
        acc = acc + (k + 4 < m ? g4 : 0.f);
        acc = acc + (k + 5 < m ? g5 : 0.f);
        acc = acc + (k + 6 < m ? g6 : 0.f);
        acc = acc + (k + 7 < m ? g7 : 0.f);
    }
    in_cur[(size_t)t * (B_ * H_) + b * H_ + tid] = acc;
}

// ---------------------------------------------------------------------------
// Fast spike check: 256 blocks x 64 threads (1 wave each), thread = (b,h) unit.
// No barriers, register double-buffered input, flags[b] set if any unit's
// pre-reset potential exceeds 0.45 (margin below V_TH=0.5).
// Also zero-fills this block's slice of out (no-spike output is exactly 0).
// ---------------------------------------------------------------------------
__global__ __launch_bounds__(64) void simfast_k(const float* __restrict__ in_cur,
                                                unsigned* __restrict__ flags,
                                                float* __restrict__ out) {
    int blk = blockIdx.x;              // B_*8 blocks
    int b = blk >> 3;
    int slice = blk & 7;
    int tid = threadIdx.x;

    // zero this block's out slice: t in [slice*32, slice*32+32), 10 outs, batch b
    #pragma unroll
    for (int i = tid; i < 320; i += 64) {
        int t = (slice << 5) + i / 10;
        int o = i - (i / 10) * 10;
        out[(size_t)t * (B_ * OUT_) + b * OUT_ + o] = 0.f;
    }

    int h = (slice << 6) + tid;
    const float* p = in_cur + b * H_ + h;
    float v = 0.f, cur = 0.f, vmax = -1e30f;
    float buf0[FB_], buf1[FB_];
    #pragma unroll
    for (int s = 0; s < FB_; ++s) buf0[s] = p[(size_t)s * (B_ * H_)];
    #pragma unroll
    for (int s = 0; s < FB_; ++s) buf1[s] = p[(size_t)(FB_ + s) * (B_ * H_)];

    for (int t0 = 0; t0 < T_; t0 += 2 * FB_) {
        #pragma unroll
        for (int s = 0; s < FB_; ++s) {
            float vd = v + 0.1f * (cur - v);
            vmax = fmaxf(vmax, vd);
            v = vd;
            cur = cur * 0.8f + buf0[s];
        }
        if (t0 + 2 * FB_ < T_) {
            #pragma unroll
            for (int s = 0; s < FB_; ++s)
                buf0[s] = p[(size_t)(t0 + 2 * FB_ + s) * (B_ * H_)];
        }
        #pragma unroll
        for (int s = 0; s < FB_; ++s) {
            float vd = v + 0.1f * (cur - v);
            vmax = fmaxf(vmax, vd);
            v = vd;
            cur = cur * 0.8f + buf1[s];
        }
        if (t0 + 3 * FB_ < T_) {
            #pragma unroll
            for (int s = 0; s < FB_; ++s)
                buf1[s] = p[(size_t)(t0 + 3 * FB_ + s) * (B_ * H_)];
        }
    }
    unsigned long long any = __ballot(vmax > 0.45f);
    if (tid == 0 && any) atomicOr(&flags[b], 1u);
}

// ---------------------------------------------------------------------------
// Exact fallback (runs only for flagged batches; rare path).
// One block per batch, per-step ballot/LDS machinery, overwrites out.
// ---------------------------------------------------------------------------
__global__ __launch_bounds__(512) void simfb_k(const unsigned* __restrict__ flags,
                                               const float* __restrict__ in_cur,
                                               const float* __restrict__ w_rec_T,
                                               const float* __restrict__ w_out,
                                               float* __restrict__ out) {
    int b = blockIdx.x;
    if (flags[b] == 0u) return;            // uniform early exit (no barriers yet)
    int tid = threadIdx.x, wid = tid >> 6, lane = tid & 63;
    __shared__ unsigned long long mword[8];
    const float* icb = in_cur + b * H_ + tid;
    float v = 0.f, cur = 0.f, vo = 0.f, io = 0.f;
    for (int t = 0; t < T_; ++t) {
        float inc = icb[(size_t)t * (B_ * H_)];
        float vd = v + 0.1f * (cur - v);
        bool z = vd > 0.5f;
        v = z ? 0.f : vd;
        unsigned long long bal = __ballot(z);
        if (lane == 0) mword[wid] = bal;
        __syncthreads();
        float c2 = cur * 0.8f + inc;       // i_dec + input first
        for (int w = 0; w < 8; ++w) {      // then rec, ascending j
            unsigned long long m = mword[w];
            while (m) {
                int j = __builtin_ctzll(m);
                c2 += w_rec_T[(size_t)((w << 6) + j) * H_ + tid];
                m &= m - 1;
            }
        }
        cur = c2;
        if (tid < OUT_) {
            float y = 0.f;
            for (int w = 0; w < 8; ++w) {
                unsigned long long m = mword[w];
                while (m) {
                    int j = __builtin_ctzll(m);
                    y += w_out[tid * H_ + (w << 6) + j];
                    m &= m - 1;
                }
            }
            float von = vo + 0.1f * (io - vo);   // uses OLD io
            io = io * 0.8f + y;
            out[(size_t)t * (B_ * OUT_) + b * OUT_ + tid] = von;
            vo = von;
        }
        __syncthreads();                   // protect mword reuse
    }
}

// ---------------------------------------------------------------------------
extern "C" void kernel_launch(void* const* d_in, const int* in_sizes, int n_in,
                              void* d_out, int out_size, void* d_ws, size_t ws_size,
                              hipStream_t stream) {
    const int*   x     = (const int*)d_in[0];
    const float* w_in  = (const float*)d_in[1];
    const float* w_rec = (const float*)d_in[2];
    const float* w_out = (const float*)d_in[3];
    float* out = (float*)d_out;

    char* ws = (char*)d_ws;
    size_t off = 0;
    int*      cnt     = (int*)(ws + off);      off += (size_t)B_ * T_ * 4;            // 32 KB
    unsigned* flags   = (unsigned*)(ws + off); off += (size_t)B_ * 4;                 // 128 B (contiguous w/ cnt)
    unsigned* data    = (unsigned*)(ws + off); off += (size_t)B_ * T_ * CAP_ * 4;     // 6 MB
    float*    w_in_T  = (float*)(ws + off);    off += (size_t)IN_ * H_ * 4;           // 8 MB
    float*    w_rec_T = (float*)(ws + off);    off += (size_t)H_ * H_ * 4;            // 1 MB
    float*    in_cur  = (float*)(ws + off);    off += (size_t)T_ * B_ * H_ * 4;       // 16 MB

    (void)hipMemsetAsync(cnt, 0, (size_t)B_ * T_ * 4 + B_ * 4, stream);  // cnt + flags

    // z=0: w_in transpose (128x16 tiles); z=1: w_rec (16x16); z=2: scatter (1024 blocks)
    prep_k<<<dim3(128, 16, 3), dim3(32, 8), 0, stream>>>(w_in, w_rec, (const int4*)x,
                                                         w_in_T, w_rec_T, cnt, data);

    incur_k<<<B_ * T_, 512, 0, stream>>>(cnt, data, w_in_T, in_cur);

    simfast_k<<<B_ * 8, 64, 0, stream>>>(in_cur, flags, out);

    simfb_k<<<B_, 512, 0, stream>>>(flags, in_cur, w_rec_T, w_out, out);
}

// Round 6
// 263.082 us; speedup vs baseline: 1.0456x; 1.0456x over previous
//
#include <hip/hip_runtime.h>

#define B_   32
#define S_   8192
#define T_   256
#define IN_  4096
#define H_   512
#define OUT_ 10
#define CAP_ 192   // max events per (b,t) bucket; max observed ~70 (Poisson(32))
#define FB_  16    // steps per register buffer in simfast_k
#define Q_   4     // buckets per incur block

// ---------------------------------------------------------------------------
// Fused prep: z=0 transpose w_in, z=1 transpose w_rec, z=2 event scatter.
// block = (32,8)
// ---------------------------------------------------------------------------
__global__ void prep_k(const float* __restrict__ w_in, const float* __restrict__ w_rec,
                       const int4* __restrict__ x,
                       float* __restrict__ w_in_T, float* __restrict__ w_rec_T,
                       int* __restrict__ cnt, unsigned* __restrict__ data) {
    int zz = blockIdx.z;
    int tx = threadIdx.x, ty = threadIdx.y;
    if (zz == 2) {
        // ---- scatter: key = (pos<<14)|(s<<1)|val; max key per pos = last event
        int flat = blockIdx.y * gridDim.x + blockIdx.x;
        if (flat >= (B_ * S_) / 256) return;
        int e = flat * 256 + ty * 32 + tx;
        int4 ev = x[e];                       // cx, cy, val, ts
        int b = e >> 13;                      // S_ = 8192
        int s = e & (S_ - 1);
        unsigned pos = (unsigned)(ev.x * ev.y);
        unsigned key = (pos << 14) | ((unsigned)s << 1) | (unsigned)ev.z;
        int bucket = b * T_ + ev.w;
        int slot = atomicAdd(&cnt[bucket], 1);
        if (slot < CAP_) data[bucket * CAP_ + slot] = key;
        return;
    }
    // ---- transpose src[R][C] -> dst[C][R]
    const float* src = zz ? w_rec : w_in;
    float* dst = zz ? w_rec_T : w_in_T;
    const int R = H_, C = zz ? H_ : IN_;
    int bx = blockIdx.x * 32, by = blockIdx.y * 32;
    if (bx >= C || by >= R) return;
    __shared__ float tile[32][33];
    #pragma unroll
    for (int k = 0; k < 32; k += 8) {
        int r = by + ty + k, c = bx + tx;
        if (r < R && c < C) tile[ty + k][tx] = src[(size_t)r * C + c];
    }
    __syncthreads();
    #pragma unroll
    for (int k = 0; k < 32; k += 8) {
        int c = bx + ty + k, r = by + tx;
        if (c < C && r < R) dst[(size_t)c * R + r] = tile[tx][ty + k];
    }
}

// ---------------------------------------------------------------------------
// Per-bucket dedup + input-current accumulation.
// Block = 512 threads handles Q_=4 buckets (same b, consecutive t).
// Dedup slice: 128 threads per bucket. plist rank = ascending key (= pos
// order, deterministic). Gather: 16 loads (4 buckets x 4) in flight/round.
// ---------------------------------------------------------------------------
__global__ __launch_bounds__(512) void incur_k(const int* __restrict__ cnt,
                                               const unsigned* __restrict__ data,
                                               const float* __restrict__ w_in_T,
                                               float* __restrict__ in_cur) {
    int b  = blockIdx.x / (T_ / Q_);
    int tg = (blockIdx.x % (T_ / Q_)) * Q_;           // first t of group
    __shared__ unsigned keys[Q_][CAP_];
    __shared__ unsigned char wf[Q_][CAP_];
    __shared__ unsigned short plist[Q_][CAP_];
    __shared__ int mq[Q_];
    int tid = threadIdx.x;
    int q = tid >> 7, lt = tid & 127;
    int bucket = b * T_ + tg + q;
    int n = cnt[bucket]; if (n > CAP_) n = CAP_;
    for (int i = lt; i < n; i += 128) keys[q][i] = data[bucket * CAP_ + i];
    if (lt < 4) plist[q][lt] = 0;                     // guard for m==0 reads
    if (lt == 0) mq[q] = 0;
    __syncthreads();
    // ---- winner flags (max key per pos, val==1), batched scans (no break)
    for (int i = lt; i < n; i += 128) {
        unsigned ki = keys[q][i], pi = ki >> 14;
        bool dead = false;
        for (int j = 0; j < n; j += 4) {
            unsigned a0 = keys[q][j];
            unsigned a1 = keys[q][j + 1 < n ? j + 1 : 0];
            unsigned a2 = keys[q][j + 2 < n ? j + 2 : 0];
            unsigned a3 = keys[q][j + 3 < n ? j + 3 : 0];
            dead |= (((a0 >> 14) == pi) & (a0 > ki));
            dead |= ((j + 1 < n) & ((a1 >> 14) == pi) & (a1 > ki));
            dead |= ((j + 2 < n) & ((a2 >> 14) == pi) & (a2 > ki));
            dead |= ((j + 3 < n) & ((a3 >> 14) == pi) & (a3 > ki));
        }
        wf[q][i] = (unsigned char)(((ki & 1u) != 0u) && !dead);
    }
    __syncthreads();
    // ---- rank by ascending key (winners have distinct pos) + compact
    for (int i = lt; i < n; i += 128) {
        if (wf[q][i]) {
            unsigned ki = keys[q][i];
            int r = 0;
            for (int j = 0; j < n; j += 4) {
                r += (int)(wf[q][j] && keys[q][j] < ki);
                r += (int)((j + 1 < n) && wf[q][j + 1] && keys[q][j + 1] < ki);
                r += (int)((j + 2 < n) && wf[q][j + 2] && keys[q][j + 2] < ki);
                r += (int)((j + 3 < n) && wf[q][j + 3] && keys[q][j + 3] < ki);
            }
            plist[q][r] = (unsigned short)(ki >> 14);
            atomicAdd(&mq[q], 1);
        }
    }
    __syncthreads();                                  // plist + mq ready
    int m0 = mq[0], m1 = mq[1], m2 = mq[2], m3 = mq[3];
    int kmax = max(max(m0, m1), max(m2, m3));
    float ac0 = 0.f, ac1 = 0.f, ac2 = 0.f, ac3 = 0.f;
    for (int k = 0; k < kmax; k += 4) {               // 16 loads in flight
        int j00 = k     < m0 ? k     : (m0 ? m0 - 1 : 0);
        int j01 = k + 1 < m0 ? k + 1 : (m0 ? m0 - 1 : 0);
        int j02 = k + 2 < m0 ? k + 2 : (m0 ? m0 - 1 : 0);
        int j03 = k + 3 < m0 ? k + 3 : (m0 ? m0 - 1 : 0);
        int j10 = k     < m1 ? k     : (m1 ? m1 - 1 : 0);
        int j11 = k + 1 < m1 ? k + 1 : (m1 ? m1 - 1 : 0);
        int j12 = k + 2 < m1 ? k + 2 : (m1 ? m1 - 1 : 0);
        int j13 = k + 3 < m1 ? k + 3 : (m1 ? m1 - 1 : 0);
        int j20 = k     < m2 ? k     : (m2 ? m2 - 1 : 0);
        int j21 = k + 1 < m2 ? k + 1 : (m2 ? m2 - 1 : 0);
        int j22 = k + 2 < m2 ? k + 2 : (m2 ? m2 - 1 : 0);
        int j23 = k + 3 < m2 ? k + 3 : (m2 ? m2 - 1 : 0);
        int j30 = k     < m3 ? k     : (m3 ? m3 - 1 : 0);
        int j31 = k + 1 < m3 ? k + 1 : (m3 ? m3 - 1 : 0);
        int j32 = k + 2 < m3 ? k + 2 : (m3 ? m3 - 1 : 0);
        int j33 = k + 3 < m3 ? k + 3 : (m3 ? m3 - 1 : 0);
        float g00 = w_in_T[(int)plist[0][j00] * H_ + tid];
        float g01 = w_in_T[(int)plist[0][j01] * H_ + tid];
        float g02 = w_in_T[(int)plist[0][j02] * H_ + tid];
        float g03 = w_in_T[(int)plist[0][j03] * H_ + tid];
        float g10 = w_in_T[(int)plist[1][j10] * H_ + tid];
        float g11 = w_in_T[(int)plist[1][j11] * H_ + tid];
        float g12 = w_in_T[(int)plist[1][j12] * H_ + tid];
        float g13 = w_in_T[(int)plist[1][j13] * H_ + tid];
        float g20 = w_in_T[(int)plist[2][j20] * H_ + tid];
        float g21 = w_in_T[(int)plist[2][j21] * H_ + tid];
        float g22 = w_in_T[(int)plist[2][j22] * H_ + tid];
        float g23 = w_in_T[(int)plist[2][j23] * H_ + tid];
        float g30 = w_in_T[(int)plist[3][j30] * H_ + tid];
        float g31 = w_in_T[(int)plist[3][j31] * H_ + tid];
        float g32 = w_in_T[(int)plist[3][j32] * H_ + tid];
        float g33 = w_in_T[(int)plist[3][j33] * H_ + tid];
        ac0 += (k     < m0 ? g00 : 0.f); ac0 += (k + 1 < m0 ? g01 : 0.f);
        ac0 += (k + 2 < m0 ? g02 : 0.f); ac0 += (k + 3 < m0 ? g03 : 0.f);
        ac1 += (k     < m1 ? g10 : 0.f); ac1 += (k + 1 < m1 ? g11 : 0.f);
        ac1 += (k + 2 < m1 ? g12 : 0.f); ac1 += (k + 3 < m1 ? g13 : 0.f);
        ac2 += (k     < m2 ? g20 : 0.f); ac2 += (k + 1 < m2 ? g21 : 0.f);
        ac2 += (k + 2 < m2 ? g22 : 0.f); ac2 += (k + 3 < m2 ? g23 : 0.f);
        ac3 += (k     < m3 ? g30 : 0.f); ac3 += (k + 1 < m3 ? g31 : 0.f);
        ac3 += (k + 2 < m3 ? g32 : 0.f); ac3 += (k + 3 < m3 ? g33 : 0.f);
    }
    in_cur[(size_t)(tg + 0) * (B_ * H_) + b * H_ + tid] = ac0;
    in_cur[(size_t)(tg + 1) * (B_ * H_) + b * H_ + tid] = ac1;
    in_cur[(size_t)(tg + 2) * (B_ * H_) + b * H_ + tid] = ac2;
    in_cur[(size_t)(tg + 3) * (B_ * H_) + b * H_ + tid] = ac3;
}

// ---------------------------------------------------------------------------
// Fast spike check: 256 blocks x 64 threads, thread = (b,h) unit.
// Flags batch b iff some unit EXACTLY crosses (vd > 0.5, same fmaf arithmetic
// as the fallback -> identical decisions). No spikes => out[:,b,:] == 0,
// which this kernel also writes.
// ---------------------------------------------------------------------------
__global__ __launch_bounds__(64) void simfast_k(const float* __restrict__ in_cur,
                                                unsigned* __restrict__ flags,
                                                float* __restrict__ out) {
    int blk = blockIdx.x;              // B_*8 blocks
    int b = blk >> 3;
    int slice = blk & 7;
    int tid = threadIdx.x;

    // zero this block's out slice: t in [slice*32, slice*32+32), 10 outs
    #pragma unroll
    for (int i = tid; i < 320; i += 64) {
        int t = (slice << 5) + i / 10;
        int o = i - (i / 10) * 10;
        out[(size_t)t * (B_ * OUT_) + b * OUT_ + o] = 0.f;
    }

    int h = (slice << 6) + tid;
    const float* p = in_cur + b * H_ + h;
    float v = 0.f, cur = 0.f, vmax = -1e30f;
    float buf0[FB_], buf1[FB_];
    #pragma unroll
    for (int s = 0; s < FB_; ++s) buf0[s] = p[(size_t)s * (B_ * H_)];
    #pragma unroll
    for (int s = 0; s < FB_; ++s) buf1[s] = p[(size_t)(FB_ + s) * (B_ * H_)];

    for (int t0 = 0; t0 < T_; t0 += 2 * FB_) {
        #pragma unroll
        for (int s = 0; s < FB_; ++s) {
            float vd = fmaf(0.1f, cur - v, v);
            vmax = fmaxf(vmax, vd);
            v = vd;
            cur = cur * 0.8f + buf0[s];
        }
        if (t0 + 2 * FB_ < T_) {
            #pragma unroll
            for (int s = 0; s < FB_; ++s)
                buf0[s] = p[(size_t)(t0 + 2 * FB_ + s) * (B_ * H_)];
        }
        #pragma unroll
        for (int s = 0; s < FB_; ++s) {
            float vd = fmaf(0.1f, cur - v, v);
            vmax = fmaxf(vmax, vd);
            v = vd;
            cur = cur * 0.8f + buf1[s];
        }
        if (t0 + 3 * FB_ < T_) {
            #pragma unroll
            for (int s = 0; s < FB_; ++s)
                buf1[s] = p[(size_t)(t0 + 3 * FB_ + s) * (B_ * H_)];
        }
    }
    unsigned long long any = __ballot(vmax > 0.5f);   // exact crossing only
    if (tid == 0 && any) atomicOr(&flags[b], 1u);
}

// ---------------------------------------------------------------------------
// Exact fallback (runs only for flagged batches; expected never on this data).
// One block per batch, per-step ballot/LDS machinery, overwrites out.
// ---------------------------------------------------------------------------
__global__ __launch_bounds__(512) void simfb_k(const unsigned* __restrict__ flags,
                                               const float* __restrict__ in_cur,
                                               const float* __restrict__ w_rec_T,
                                               const float* __restrict__ w_out,
                                               float* __restrict__ out) {
    int b = blockIdx.x;
    if (flags[b] == 0u) return;            // uniform early exit (no barriers yet)
    int tid = threadIdx.x, wid = tid >> 6, lane = tid & 63;
    __shared__ unsigned long long mword[8];
    const float* icb = in_cur + b * H_ + tid;
    float v = 0.f, cur = 0.f, vo = 0.f, io = 0.f;
    for (int t = 0; t < T_; ++t) {
        float inc = icb[(size_t)t * (B_ * H_)];
        float vd = fmaf(0.1f, cur - v, v);
        bool z = vd > 0.5f;
        v = z ? 0.f : vd;
        unsigned long long bal = __ballot(z);
        if (lane == 0) mword[wid] = bal;
        __syncthreads();
        float c2 = cur * 0.8f + inc;       // i_dec + input first
        for (int w = 0; w < 8; ++w) {      // then rec, ascending j
            unsigned long long m = mword[w];
            while (m) {
                int j = __builtin_ctzll(m);
                c2 += w_rec_T[(size_t)((w << 6) + j) * H_ + tid];
                m &= m - 1;
            }
        }
        cur = c2;
        if (tid < OUT_) {
            float y = 0.f;
            for (int w = 0; w < 8; ++w) {
                unsigned long long m = mword[w];
                while (m) {
                    int j = __builtin_ctzll(m);
                    y += w_out[tid * H_ + (w << 6) + j];
                    m &= m - 1;
                }
            }
            float von = fmaf(0.1f, io - vo, vo);   // uses OLD io
            io = io * 0.8f + y;
            out[(size_t)t * (B_ * OUT_) + b * OUT_ + tid] = von;
            vo = von;
        }
        __syncthreads();                   // protect mword reuse
    }
}

// ---------------------------------------------------------------------------
extern "C" void kernel_launch(void* const* d_in, const int* in_sizes, int n_in,
                              void* d_out, int out_size, void* d_ws, size_t ws_size,
                              hipStream_t stream) {
    const int*   x     = (const int*)d_in[0];
    const float* w_in  = (const float*)d_in[1];
    const float* w_rec = (const float*)d_in[2];
    const float* w_out = (const float*)d_in[3];
    float* out = (float*)d_out;

    char* ws = (char*)d_ws;
    size_t off = 0;
    int*      cnt     = (int*)(ws + off);      off += (size_t)B_ * T_ * 4;            // 32 KB
    unsigned* flags   = (unsigned*)(ws + off); off += (size_t)B_ * 4;                 // 128 B (contiguous w/ cnt)
    unsigned* data    = (unsigned*)(ws + off); off += (size_t)B_ * T_ * CAP_ * 4;     // 6 MB
    float*    w_in_T  = (float*)(ws + off);    off += (size_t)IN_ * H_ * 4;           // 8 MB
    float*    w_rec_T = (float*)(ws + off);    off += (size_t)H_ * H_ * 4;            // 1 MB
    float*    in_cur  = (float*)(ws + off);    off += (size_t)T_ * B_ * H_ * 4;       // 16 MB

    (void)hipMemsetAsync(cnt, 0, (size_t)B_ * T_ * 4 + B_ * 4, stream);  // cnt + flags

    // z=0: w_in transpose (128x16 tiles); z=1: w_rec (16x16); z=2: scatter (1024 blocks)
    prep_k<<<dim3(128, 16, 3), dim3(32, 8), 0, stream>>>(w_in, w_rec, (const int4*)x,
                                                         w_in_T, w_rec_T, cnt, data);

    incur_k<<<B_ * (T_ / Q_), 512, 0, stream>>>(cnt, data, w_in_T, in_cur);

    simfast_k<<<B_ * 8, 64, 0, stream>>>(in_cur, flags, out);

    simfb_k<<<B_, 512, 0, stream>>>(flags, in_cur, w_rec_T, w_out, out);
}

// Round 7
// 97.296 us; speedup vs baseline: 2.8272x; 2.7039x over previous
//
#include <hip/hip_runtime.h>

#define B_   32
#define S_   8192
#define T_   256
#define IN_  4096
#define H_   512
#define OUT_ 10
#define CAP_ 192   // max events per (b,t) bucket; max observed ~70 (Poisson(32))
#define FB_  16    // steps per register buffer in simfast_k
#define Q_   4     // buckets per incur block
#define CH2  16    // steps per speculative chunk in simfb_k

// ---------------------------------------------------------------------------
// Fused prep: z=0 transpose w_in, z=1 transpose w_rec, z=2 event scatter.
// block = (32,8)
// ---------------------------------------------------------------------------
__global__ void prep_k(const float* __restrict__ w_in, const float* __restrict__ w_rec,
                       const int4* __restrict__ x,
                       float* __restrict__ w_in_T, float* __restrict__ w_rec_T,
                       int* __restrict__ cnt, unsigned* __restrict__ data) {
    int zz = blockIdx.z;
    int tx = threadIdx.x, ty = threadIdx.y;
    if (zz == 2) {
        // ---- scatter: key = (pos<<14)|(s<<1)|val; max key per pos = last event
        int flat = blockIdx.y * gridDim.x + blockIdx.x;
        if (flat >= (B_ * S_) / 256) return;
        int e = flat * 256 + ty * 32 + tx;
        int4 ev = x[e];                       // cx, cy, val, ts
        int b = e >> 13;                      // S_ = 8192
        int s = e & (S_ - 1);
        unsigned pos = (unsigned)(ev.x * ev.y);
        unsigned key = (pos << 14) | ((unsigned)s << 1) | (unsigned)ev.z;
        int bucket = b * T_ + ev.w;
        int slot = atomicAdd(&cnt[bucket], 1);
        if (slot < CAP_) data[bucket * CAP_ + slot] = key;
        return;
    }
    // ---- transpose src[R][C] -> dst[C][R]
    const float* src = zz ? w_rec : w_in;
    float* dst = zz ? w_rec_T : w_in_T;
    const int R = H_, C = zz ? H_ : IN_;
    int bx = blockIdx.x * 32, by = blockIdx.y * 32;
    if (bx >= C || by >= R) return;
    __shared__ float tile[32][33];
    #pragma unroll
    for (int k = 0; k < 32; k += 8) {
        int r = by + ty + k, c = bx + tx;
        if (r < R && c < C) tile[ty + k][tx] = src[(size_t)r * C + c];
    }
    __syncthreads();
    #pragma unroll
    for (int k = 0; k < 32; k += 8) {
        int c = bx + ty + k, r = by + tx;
        if (c < C && r < R) dst[(size_t)c * R + r] = tile[tx][ty + k];
    }
}

// ---------------------------------------------------------------------------
// Per-bucket dedup + input-current accumulation.
// Block = 512 threads handles Q_=4 buckets (same b, consecutive t).
// Dedup slice: 128 threads per bucket. plist rank = ascending key (= pos
// order, deterministic). Gather: 16 loads (4 buckets x 4) in flight/round.
// ---------------------------------------------------------------------------
__global__ __launch_bounds__(512) void incur_k(const int* __restrict__ cnt,
                                               const unsigned* __restrict__ data,
                                               const float* __restrict__ w_in_T,
                                               float* __restrict__ in_cur) {
    int b  = blockIdx.x / (T_ / Q_);
    int tg = (blockIdx.x % (T_ / Q_)) * Q_;           // first t of group
    __shared__ unsigned keys[Q_][CAP_];
    __shared__ unsigned char wf[Q_][CAP_];
    __shared__ unsigned short plist[Q_][CAP_];
    __shared__ int mq[Q_];
    int tid = threadIdx.x;
    int q = tid >> 7, lt = tid & 127;
    int bucket = b * T_ + tg + q;
    int n = cnt[bucket]; if (n > CAP_) n = CAP_;
    for (int i = lt; i < n; i += 128) keys[q][i] = data[bucket * CAP_ + i];
    if (lt < 4) plist[q][lt] = 0;                     // guard for m==0 reads
    if (lt == 0) mq[q] = 0;
    __syncthreads();
    // ---- winner flags (max key per pos, val==1), batched scans (no break)
    for (int i = lt; i < n; i += 128) {
        unsigned ki = keys[q][i], pi = ki >> 14;
        bool dead = false;
        for (int j = 0; j < n; j += 4) {
            unsigned a0 = keys[q][j];
            unsigned a1 = keys[q][j + 1 < n ? j + 1 : 0];
            unsigned a2 = keys[q][j + 2 < n ? j + 2 : 0];
            unsigned a3 = keys[q][j + 3 < n ? j + 3 : 0];
            dead |= (((a0 >> 14) == pi) & (a0 > ki));
            dead |= ((j + 1 < n) & ((a1 >> 14) == pi) & (a1 > ki));
            dead |= ((j + 2 < n) & ((a2 >> 14) == pi) & (a2 > ki));
            dead |= ((j + 3 < n) & ((a3 >> 14) == pi) & (a3 > ki));
        }
        wf[q][i] = (unsigned char)(((ki & 1u) != 0u) && !dead);
    }
    __syncthreads();
    // ---- rank by ascending key (winners have distinct pos) + compact
    for (int i = lt; i < n; i += 128) {
        if (wf[q][i]) {
            unsigned ki = keys[q][i];
            int r = 0;
            for (int j = 0; j < n; j += 4) {
                r += (int)(wf[q][j] && keys[q][j] < ki);
                r += (int)((j + 1 < n) && wf[q][j + 1] && keys[q][j + 1] < ki);
                r += (int)((j + 2 < n) && wf[q][j + 2] && keys[q][j + 2] < ki);
                r += (int)((j + 3 < n) && wf[q][j + 3] && keys[q][j + 3] < ki);
            }
            plist[q][r] = (unsigned short)(ki >> 14);
            atomicAdd(&mq[q], 1);
        }
    }
    __syncthreads();                                  // plist + mq ready
    int m0 = mq[0], m1 = mq[1], m2 = mq[2], m3 = mq[3];
    int kmax = max(max(m0, m1), max(m2, m3));
    float ac0 = 0.f, ac1 = 0.f, ac2 = 0.f, ac3 = 0.f;
    for (int k = 0; k < kmax; k += 4) {               // 16 loads in flight
        int j00 = k     < m0 ? k     : (m0 ? m0 - 1 : 0);
        int j01 = k + 1 < m0 ? k + 1 : (m0 ? m0 - 1 : 0);
        int j02 = k + 2 < m0 ? k + 2 : (m0 ? m0 - 1 : 0);
        int j03 = k + 3 < m0 ? k + 3 : (m0 ? m0 - 1 : 0);
        int j10 = k     < m1 ? k     : (m1 ? m1 - 1 : 0);
        int j11 = k + 1 < m1 ? k + 1 : (m1 ? m1 - 1 : 0);
        int j12 = k + 2 < m1 ? k + 2 : (m1 ? m1 - 1 : 0);
        int j13 = k + 3 < m1 ? k + 3 : (m1 ? m1 - 1 : 0);
        int j20 = k     < m2 ? k     : (m2 ? m2 - 1 : 0);
        int j21 = k + 1 < m2 ? k + 1 : (m2 ? m2 - 1 : 0);
        int j22 = k + 2 < m2 ? k + 2 : (m2 ? m2 - 1 : 0);
        int j23 = k + 3 < m2 ? k + 3 : (m2 ? m2 - 1 : 0);
        int j30 = k     < m3 ? k     : (m3 ? m3 - 1 : 0);
        int j31 = k + 1 < m3 ? k + 1 : (m3 ? m3 - 1 : 0);
        int j32 = k + 2 < m3 ? k + 2 : (m3 ? m3 - 1 : 0);
        int j33 = k + 3 < m3 ? k + 3 : (m3 ? m3 - 1 : 0);
        float g00 = w_in_T[(int)plist[0][j00] * H_ + tid];
        float g01 = w_in_T[(int)plist[0][j01] * H_ + tid];
        float g02 = w_in_T[(int)plist[0][j02] * H_ + tid];
        float g03 = w_in_T[(int)plist[0][j03] * H_ + tid];
        float g10 = w_in_T[(int)plist[1][j10] * H_ + tid];
        float g11 = w_in_T[(int)plist[1][j11] * H_ + tid];
        float g12 = w_in_T[(int)plist[1][j12] * H_ + tid];
        float g13 = w_in_T[(int)plist[1][j13] * H_ + tid];
        float g20 = w_in_T[(int)plist[2][j20] * H_ + tid];
        float g21 = w_in_T[(int)plist[2][j21] * H_ + tid];
        float g22 = w_in_T[(int)plist[2][j22] * H_ + tid];
        float g23 = w_in_T[(int)plist[2][j23] * H_ + tid];
        float g30 = w_in_T[(int)plist[3][j30] * H_ + tid];
        float g31 = w_in_T[(int)plist[3][j31] * H_ + tid];
        float g32 = w_in_T[(int)plist[3][j32] * H_ + tid];
        float g33 = w_in_T[(int)plist[3][j33] * H_ + tid];
        ac0 += (k     < m0 ? g00 : 0.f); ac0 += (k + 1 < m0 ? g01 : 0.f);
        ac0 += (k + 2 < m0 ? g02 : 0.f); ac0 += (k + 3 < m0 ? g03 : 0.f);
        ac1 += (k     < m1 ? g10 : 0.f); ac1 += (k + 1 < m1 ? g11 : 0.f);
        ac1 += (k + 2 < m1 ? g12 : 0.f); ac1 += (k + 3 < m1 ? g13 : 0.f);
        ac2 += (k     < m2 ? g20 : 0.f); ac2 += (k + 1 < m2 ? g21 : 0.f);
        ac2 += (k + 2 < m2 ? g22 : 0.f); ac2 += (k + 3 < m2 ? g23 : 0.f);
        ac3 += (k     < m3 ? g30 : 0.f); ac3 += (k + 1 < m3 ? g31 : 0.f);
        ac3 += (k + 2 < m3 ? g32 : 0.f); ac3 += (k + 3 < m3 ? g33 : 0.f);
    }
    in_cur[(size_t)(tg + 0) * (B_ * H_) + b * H_ + tid] = ac0;
    in_cur[(size_t)(tg + 1) * (B_ * H_) + b * H_ + tid] = ac1;
    in_cur[(size_t)(tg + 2) * (B_ * H_) + b * H_ + tid] = ac2;
    in_cur[(size_t)(tg + 3) * (B_ * H_) + b * H_ + tid] = ac3;
}

// ---------------------------------------------------------------------------
// Fast spike check: 256 blocks x 64 threads, thread = (b,h) unit.
// Flags batch b iff some unit EXACTLY crosses (vd > 0.5, same fmaf arithmetic
// as the fallback -> identical decisions). No spikes => out[:,b,:] == 0,
// which this kernel also writes.
// ---------------------------------------------------------------------------
__global__ __launch_bounds__(64) void simfast_k(const float* __restrict__ in_cur,
                                                unsigned* __restrict__ flags,
                                                float* __restrict__ out) {
    int blk = blockIdx.x;              // B_*8 blocks
    int b = blk >> 3;
    int slice = blk & 7;
    int tid = threadIdx.x;

    // zero this block's out slice: t in [slice*32, slice*32+32), 10 outs
    #pragma unroll
    for (int i = tid; i < 320; i += 64) {
        int t = (slice << 5) + i / 10;
        int o = i - (i / 10) * 10;
        out[(size_t)t * (B_ * OUT_) + b * OUT_ + o] = 0.f;
    }

    int h = (slice << 6) + tid;
    const float* p = in_cur + b * H_ + h;
    float v = 0.f, cur = 0.f, vmax = -1e30f;
    float buf0[FB_], buf1[FB_];
    #pragma unroll
    for (int s = 0; s < FB_; ++s) buf0[s] = p[(size_t)s * (B_ * H_)];
    #pragma unroll
    for (int s = 0; s < FB_; ++s) buf1[s] = p[(size_t)(FB_ + s) * (B_ * H_)];

    for (int t0 = 0; t0 < T_; t0 += 2 * FB_) {
        #pragma unroll
        for (int s = 0; s < FB_; ++s) {
            float vd = fmaf(0.1f, cur - v, v);
            vmax = fmaxf(vmax, vd);
            v = vd;
            cur = cur * 0.8f + buf0[s];
        }
        if (t0 + 2 * FB_ < T_) {
            #pragma unroll
            for (int s = 0; s < FB_; ++s)
                buf0[s] = p[(size_t)(t0 + 2 * FB_ + s) * (B_ * H_)];
        }
        #pragma unroll
        for (int s = 0; s < FB_; ++s) {
            float vd = fmaf(0.1f, cur - v, v);
            vmax = fmaxf(vmax, vd);
            v = vd;
            cur = cur * 0.8f + buf1[s];
        }
        if (t0 + 3 * FB_ < T_) {
            #pragma unroll
            for (int s = 0; s < FB_; ++s)
                buf1[s] = p[(size_t)(t0 + 3 * FB_ + s) * (B_ * H_)];
        }
    }
    unsigned long long any = __ballot(vmax > 0.5f);   // exact crossing only
    if (tid == 0 && any) atomicOr(&flags[b], 1u);
}

// ---------------------------------------------------------------------------
// Exact fallback (runs only for flagged batches). Speculative 16-step chunks:
// register-buffered inputs (one latency wait per chunk), pure-VALU fast path,
// __syncthreads_or spike check; on spike, exact per-step replay of the chunk
// from a register snapshot with ballot/LDS machinery in numpy order.
// ---------------------------------------------------------------------------
__global__ __launch_bounds__(512) void simfb_k(const unsigned* __restrict__ flags,
                                               const float* __restrict__ in_cur,
                                               const float* __restrict__ w_rec_T,
                                               const float* __restrict__ w_out,
                                               float* __restrict__ out) {
    int b = blockIdx.x;
    if (flags[b] == 0u) return;            // uniform early exit (no barriers yet)
    int tid = threadIdx.x, wid = tid >> 6, lane = tid & 63;
    __shared__ unsigned long long mword[8];
    const float* icb = in_cur + b * H_ + tid;
    float* outp = out + b * OUT_ + tid;    // valid when tid < OUT_
    float v = 0.f, cur = 0.f, vo = 0.f, io = 0.f;

    for (int c = 0; c < T_ / CH2; ++c) {
        float ib[CH2];
        #pragma unroll
        for (int s = 0; s < CH2; ++s)      // 16 independent loads, one wait
            ib[s] = icb[(size_t)(c * CH2 + s) * (B_ * H_)];
        float v0 = v, cur0 = cur, vo0 = vo, io0 = io;   // rollback snapshot
        float vmax = -1e30f;
        // ---- fast path: assume no spikes in this chunk
        #pragma unroll
        for (int s = 0; s < CH2; ++s) {
            float vd = fmaf(0.1f, cur - v, v);
            vmax = fmaxf(vmax, vd);
            v = vd;
            cur = cur * 0.8f + ib[s];
            if (tid < OUT_) {
                float von = fmaf(0.1f, io - vo, vo);    // uses OLD io
                io *= 0.8f;                             // y == 0
                outp[(size_t)(c * CH2 + s) * (B_ * OUT_)] = von;
                vo = von;
            }
        }
        int any = __syncthreads_or(vmax > 0.5f);
        if (any) {
            // ---- exact replay with spikes (numpy summation order)
            v = v0; cur = cur0; vo = vo0; io = io0;
            #pragma unroll 1
            for (int s = 0; s < CH2; ++s) {
                float vd = fmaf(0.1f, cur - v, v);
                bool z = vd > 0.5f;
                v = z ? 0.f : vd;
                unsigned long long bal = __ballot(z);
                if (lane == 0) mword[wid] = bal;
                __syncthreads();
                float c2 = cur * 0.8f + ib[s];          // i_dec + input first
                for (int w = 0; w < 8; ++w) {           // then rec, ascending j
                    unsigned long long m = mword[w];
                    while (m) {
                        int j = __builtin_ctzll(m);
                        c2 += w_rec_T[(size_t)((w << 6) + j) * H_ + tid];
                        m &= m - 1;
                    }
                }
                cur = c2;
                if (tid < OUT_) {
                    float y = 0.f;
                    for (int w = 0; w < 8; ++w) {
                        unsigned long long m = mword[w];
                        while (m) {
                            int j = __builtin_ctzll(m);
                            y += w_out[tid * H_ + (w << 6) + j];
                            m &= m - 1;
                        }
                    }
                    float von = fmaf(0.1f, io - vo, vo);   // uses OLD io
                    io = io * 0.8f + y;
                    outp[(size_t)(c * CH2 + s) * (B_ * OUT_)] = von;  // overwrite
                    vo = von;
                }
                __syncthreads();                        // protect mword reuse
            }
        }
    }
}

// ---------------------------------------------------------------------------
extern "C" void kernel_launch(void* const* d_in, const int* in_sizes, int n_in,
                              void* d_out, int out_size, void* d_ws, size_t ws_size,
                              hipStream_t stream) {
    const int*   x     = (const int*)d_in[0];
    const float* w_in  = (const float*)d_in[1];
    const float* w_rec = (const float*)d_in[2];
    const float* w_out = (const float*)d_in[3];
    float* out = (float*)d_out;

    char* ws = (char*)d_ws;
    size_t off = 0;
    int*      cnt     = (int*)(ws + off);      off += (size_t)B_ * T_ * 4;            // 32 KB
    unsigned* flags   = (unsigned*)(ws + off); off += (size_t)B_ * 4;                 // 128 B (contiguous w/ cnt)
    unsigned* data    = (unsigned*)(ws + off); off += (size_t)B_ * T_ * CAP_ * 4;     // 6 MB
    float*    w_in_T  = (float*)(ws + off);    off += (size_t)IN_ * H_ * 4;           // 8 MB
    float*    w_rec_T = (float*)(ws + off);    off += (size_t)H_ * H_ * 4;            // 1 MB
    float*    in_cur  = (float*)(ws + off);    off += (size_t)T_ * B_ * H_ * 4;       // 16 MB

    (void)hipMemsetAsync(cnt, 0, (size_t)B_ * T_ * 4 + B_ * 4, stream);  // cnt + flags

    // z=0: w_in transpose (128x16 tiles); z=1: w_rec (16x16); z=2: scatter (1024 blocks)
    prep_k<<<dim3(128, 16, 3), dim3(32, 8), 0, stream>>>(w_in, w_rec, (const int4*)x,
                                                         w_in_T, w_rec_T, cnt, data);

    incur_k<<<B_ * (T_ / Q_), 512, 0, stream>>>(cnt, data, w_in_T, in_cur);

    simfast_k<<<B_ * 8, 64, 0, stream>>>(in_cur, flags, out);

    simfb_k<<<B_, 512, 0, stream>>>(flags, in_cur, w_rec_T, w_out, out);
}

// Round 8
// 89.933 us; speedup vs baseline: 3.0587x; 1.0819x over previous
//
#include <hip/hip_runtime.h>

#define B_   32
#define S_   8192
#define T_   256
#define IN_  4096
#define H_   512
#define OUT_ 10
#define CAP_ 192   // max events per (b,t) bucket; max observed ~70 (Poisson(32))
#define Q_   4     // buckets per incur block
#define CH2  16    // steps per speculative chunk in sim_k
#define NCH2 (T_ / CH2)
#define PADC (CAP_ + 8)

// ---------------------------------------------------------------------------
// Fused prep: z=0 transpose w_in, z=1 transpose w_rec, z=2 event scatter.
// block = (32,8)
// ---------------------------------------------------------------------------
__global__ void prep_k(const float* __restrict__ w_in, const float* __restrict__ w_rec,
                       const int4* __restrict__ x,
                       float* __restrict__ w_in_T, float* __restrict__ w_rec_T,
                       int* __restrict__ cnt, unsigned* __restrict__ data) {
    int zz = blockIdx.z;
    int tx = threadIdx.x, ty = threadIdx.y;
    if (zz == 2) {
        // ---- scatter: key = (pos<<14)|(s<<1)|val; max key per pos = last event
        int flat = blockIdx.y * gridDim.x + blockIdx.x;
        if (flat >= (B_ * S_) / 256) return;
        int e = flat * 256 + ty * 32 + tx;
        int4 ev = x[e];                       // cx, cy, val, ts
        int b = e >> 13;                      // S_ = 8192
        int s = e & (S_ - 1);
        unsigned pos = (unsigned)(ev.x * ev.y);
        unsigned key = (pos << 14) | ((unsigned)s << 1) | (unsigned)ev.z;
        int bucket = b * T_ + ev.w;
        int slot = atomicAdd(&cnt[bucket], 1);
        if (slot < CAP_) data[bucket * CAP_ + slot] = key;
        return;
    }
    // ---- transpose src[R][C] -> dst[C][R]
    const float* src = zz ? w_rec : w_in;
    float* dst = zz ? w_rec_T : w_in_T;
    const int R = H_, C = zz ? H_ : IN_;
    int bx = blockIdx.x * 32, by = blockIdx.y * 32;
    if (bx >= C || by >= R) return;
    __shared__ float tile[32][33];
    #pragma unroll
    for (int k = 0; k < 32; k += 8) {
        int r = by + ty + k, c = bx + tx;
        if (r < R && c < C) tile[ty + k][tx] = src[(size_t)r * C + c];
    }
    __syncthreads();
    #pragma unroll
    for (int k = 0; k < 32; k += 8) {
        int c = bx + ty + k, r = by + tx;
        if (c < C && r < R) dst[(size_t)c * R + r] = tile[tx][ty + k];
    }
}

// ---------------------------------------------------------------------------
// Per-bucket dedup + input-current accumulation.
// Block = 512 threads = 4 buckets x 128 threads; thread owns 4 h (float4).
// plist pre-filled with IN_ (zero row) -> gather loop has NO clamps/selects.
// LDS arrays padded (+8) to de-conflict the 4 q-slices' parallel scans.
// ---------------------------------------------------------------------------
__global__ __launch_bounds__(512) void incur_k(const int* __restrict__ cnt,
                                               const unsigned* __restrict__ data,
                                               const float* __restrict__ w_in_T,
                                               float* __restrict__ in_cur) {
    int b  = blockIdx.x / (T_ / Q_);
    int tg = (blockIdx.x % (T_ / Q_)) * Q_;           // first t of group
    __shared__ unsigned keys[Q_][PADC];
    __shared__ unsigned char wf[Q_][PADC];
    __shared__ unsigned short plist[Q_][PADC];
    __shared__ int mq[Q_];
    int tid = threadIdx.x;
    int q = tid >> 7, lt = tid & 127;
    int bucket = b * T_ + tg + q;
    int n = cnt[bucket]; if (n > CAP_) n = CAP_;
    for (int i = lt; i < n; i += 128) keys[q][i] = data[bucket * CAP_ + i];
    #pragma unroll
    for (int i = lt; i < PADC; i += 128) plist[q][i] = (unsigned short)IN_;  // zero-row pad
    if (lt == 0) mq[q] = 0;
    __syncthreads();
    // ---- winner flags (max key per pos, val==1), batched scans (no break)
    for (int i = lt; i < n; i += 128) {
        unsigned ki = keys[q][i], pi = ki >> 14;
        bool dead = false;
        for (int j = 0; j < n; j += 4) {
            unsigned a0 = keys[q][j];
            unsigned a1 = keys[q][j + 1 < n ? j + 1 : 0];
            unsigned a2 = keys[q][j + 2 < n ? j + 2 : 0];
            unsigned a3 = keys[q][j + 3 < n ? j + 3 : 0];
            dead |= (((a0 >> 14) == pi) & (a0 > ki));
            dead |= ((j + 1 < n) & ((a1 >> 14) == pi) & (a1 > ki));
            dead |= ((j + 2 < n) & ((a2 >> 14) == pi) & (a2 > ki));
            dead |= ((j + 3 < n) & ((a3 >> 14) == pi) & (a3 > ki));
        }
        wf[q][i] = (unsigned char)(((ki & 1u) != 0u) && !dead);
    }
    __syncthreads();
    // ---- rank by ascending key (winners have distinct pos) + compact
    for (int i = lt; i < n; i += 128) {
        if (wf[q][i]) {
            unsigned ki = keys[q][i];
            int r = 0;
            for (int j = 0; j < n; j += 4) {
                r += (int)(wf[q][j] && keys[q][j] < ki);
                r += (int)((j + 1 < n) && wf[q][j + 1] && keys[q][j + 1] < ki);
                r += (int)((j + 2 < n) && wf[q][j + 2] && keys[q][j + 2] < ki);
                r += (int)((j + 3 < n) && wf[q][j + 3] && keys[q][j + 3] < ki);
            }
            plist[q][r] = (unsigned short)(ki >> 14);
            atomicAdd(&mq[q], 1);
        }
    }
    __syncthreads();                                  // plist + mq ready
    // ---- gather: thread sums rows for h = lt*4 .. lt*4+3 (float4)
    int m = mq[q];
    const float4* w4 = (const float4*)w_in_T;         // [IN_+1][128]
    float4 acc = make_float4(0.f, 0.f, 0.f, 0.f);
    for (int k = 0; k < m; k += 4) {                  // pads read the zero row
        float4 g0 = w4[(size_t)plist[q][k + 0] * 128 + lt];
        float4 g1 = w4[(size_t)plist[q][k + 1] * 128 + lt];
        float4 g2 = w4[(size_t)plist[q][k + 2] * 128 + lt];
        float4 g3 = w4[(size_t)plist[q][k + 3] * 128 + lt];
        acc.x = (((acc.x + g0.x) + g1.x) + g2.x) + g3.x;
        acc.y = (((acc.y + g0.y) + g1.y) + g2.y) + g3.y;
        acc.z = (((acc.z + g0.z) + g1.z) + g2.z) + g3.z;
        acc.w = (((acc.w + g0.w) + g1.w) + g2.w) + g3.w;
    }
    ((float4*)(in_cur + (size_t)(tg + q) * (B_ * H_) + b * H_))[lt] = acc;
}

// ---------------------------------------------------------------------------
// Merged simulation: 32 blocks x 512 threads, thread = hidden unit of batch b.
// Speculative 16-step chunks (register double-buffered inputs, pure VALU, one
// __syncthreads_or per chunk). On any exact crossing (or carried-in spike
// state), rollback + exact per-step replay with CORRECT z_prev timing:
// i_new = i_dec + input + z_prev @ w_rec.T ; y = z_new @ w_out.T.
// ---------------------------------------------------------------------------
__global__ __launch_bounds__(512) void sim_k(const float* __restrict__ in_cur,
                                             const float* __restrict__ w_rec_T,
                                             const float* __restrict__ w_out,
                                             float* __restrict__ out) {
    int b = blockIdx.x;
    int tid = threadIdx.x, wid = tid >> 6, lane = tid & 63;
    __shared__ unsigned long long mword[2][8];
    const float* icb = in_cur + b * H_ + tid;
    float* outp = out + b * OUT_ + tid;    // valid when tid < OUT_
    float v = 0.f, cur = 0.f, vo = 0.f, io = 0.f;
    bool zst = false;                      // z of previous step (carried)

    float bufA[CH2], bufB[CH2];
    #pragma unroll
    for (int s = 0; s < CH2; ++s) bufA[s] = icb[(size_t)s * (B_ * H_)];
    #pragma unroll
    for (int s = 0; s < CH2; ++s) bufB[s] = icb[(size_t)(CH2 + s) * (B_ * H_)];

#define PROCESS(BUF, CIDX)                                                     \
    do {                                                                       \
        int c_ = (CIDX);                                                       \
        float v0 = v, cur0 = cur, vo0 = vo, io0 = io;                          \
        bool zst0 = zst;                                                       \
        float vmax = -1e30f;                                                   \
        _Pragma("unroll")                                                      \
        for (int s = 0; s < CH2; ++s) {                                        \
            float vd = fmaf(0.1f, cur - v, v);                                 \
            vmax = fmaxf(vmax, vd);                                            \
            v = vd;                                                            \
            cur = cur * 0.8f + BUF[s];                                         \
            if (tid < OUT_) {                                                  \
                float von = fmaf(0.1f, io - vo, vo);                           \
                io *= 0.8f;                                                    \
                outp[(size_t)(c_ * CH2 + s) * (B_ * OUT_)] = von;              \
                vo = von;                                                      \
            }                                                                  \
        }                                                                      \
        int any = __syncthreads_or((vmax > 0.5f) || zst0);                     \
        if (any) {                                                             \
            v = v0; cur = cur0; vo = vo0; io = io0; zst = zst0;                \
            unsigned long long sb = __ballot(zst);                             \
            if (lane == 0) mword[1][wid] = sb;   /* s=0 reads mword[1] */      \
            __syncthreads();                                                   \
            for (int s = 0; s < CH2; ++s) {                                    \
                int p = s & 1;                                                 \
                float vd = fmaf(0.1f, cur - v, v);                             \
                bool z = vd > 0.5f;                                            \
                v = z ? 0.f : vd;                                              \
                unsigned long long bal = __ballot(z);                          \
                if (lane == 0) mword[p][wid] = bal;                            \
                __syncthreads();                                               \
                float c2 = cur * 0.8f + BUF[s];      /* i_dec + input */       \
                for (int w = 0; w < 8; ++w) {        /* + z_prev @ w_rec.T */  \
                    unsigned long long mm = mword[p ^ 1][w];                   \
                    while (mm) {                                               \
                        int j = __builtin_ctzll(mm);                           \
                        c2 += w_rec_T[(size_t)((w << 6) + j) * H_ + tid];      \
                        mm &= mm - 1;                                          \
                    }                                                          \
                }                                                              \
                cur = c2;                                                      \
                if (tid < OUT_) {                                              \
                    float y = 0.f;                                             \
                    for (int w = 0; w < 8; ++w) {    /* z_new @ w_out.T */     \
                        unsigned long long mm = mword[p][w];                   \
                        while (mm) {                                           \
                            int j = __builtin_ctzll(mm);                       \
                            y += w_out[tid * H_ + (w << 6) + j];               \
                            mm &= mm - 1;                                      \
                        }                                                      \
                    }                                                          \
                    float von = fmaf(0.1f, io - vo, vo);                       \
                    io = io * 0.8f + y;                                        \
                    outp[(size_t)(c_ * CH2 + s) * (B_ * OUT_)] = von;          \
                    vo = von;                                                  \
                }                                                              \
                zst = z;                                                       \
                __syncthreads();                     /* protect mword reuse */ \
            }                                                                  \
        }                                                                      \
    } while (0)

    for (int c = 0; c < NCH2; c += 2) {
        PROCESS(bufA, c);
        if (c + 2 < NCH2) {
            #pragma unroll
            for (int s = 0; s < CH2; ++s)
                bufA[s] = icb[(size_t)((c + 2) * CH2 + s) * (B_ * H_)];
        }
        PROCESS(bufB, c + 1);
        if (c + 3 < NCH2) {
            #pragma unroll
            for (int s = 0; s < CH2; ++s)
                bufB[s] = icb[(size_t)((c + 3) * CH2 + s) * (B_ * H_)];
        }
    }
#undef PROCESS
}

// ---------------------------------------------------------------------------
extern "C" void kernel_launch(void* const* d_in, const int* in_sizes, int n_in,
                              void* d_out, int out_size, void* d_ws, size_t ws_size,
                              hipStream_t stream) {
    const int*   x     = (const int*)d_in[0];
    const float* w_in  = (const float*)d_in[1];
    const float* w_rec = (const float*)d_in[2];
    const float* w_out = (const float*)d_in[3];
    float* out = (float*)d_out;

    char* ws = (char*)d_ws;
    size_t off = 0;
    int*      cnt     = (int*)(ws + off);      off += (size_t)B_ * T_ * 4;            // 32 KB
    unsigned* data    = (unsigned*)(ws + off); off += (size_t)B_ * T_ * CAP_ * 4;     // 6 MB
    float*    w_in_T  = (float*)(ws + off);    off += (size_t)(IN_ + 1) * H_ * 4;     // 8 MB + zero row
    float*    w_rec_T = (float*)(ws + off);    off += (size_t)H_ * H_ * 4;            // 1 MB
    float*    in_cur  = (float*)(ws + off);    off += (size_t)T_ * B_ * H_ * 4;       // 16 MB

    (void)hipMemsetAsync(cnt, 0, (size_t)B_ * T_ * 4, stream);
    (void)hipMemsetAsync(w_in_T + (size_t)IN_ * H_, 0, H_ * 4, stream);   // zero pad row

    // z=0: w_in transpose (128x16 tiles); z=1: w_rec (16x16); z=2: scatter (1024 blocks)
    prep_k<<<dim3(128, 16, 3), dim3(32, 8), 0, stream>>>(w_in, w_rec, (const int4*)x,
                                                         w_in_T, w_rec_T, cnt, data);

    incur_k<<<B_ * (T_ / Q_), 512, 0, stream>>>(cnt, data, w_in_T, in_cur);

    sim_k<<<B_, 512, 0, stream>>>(in_cur, w_rec_T, w_out, out);
}